// Round 14
// baseline (409.878 us; speedup 1.0000x reference)
//
#include <hip/hip_runtime.h>
#include <math.h>

// Problem constants
#define BS    2048            // batch
#define NROW  4096            // B*V = N
#define EDIM  256
#define INVT  (1.0f/0.07f)
#define KEXP  20.609929155556623f   // INVT * log2(e): exp(x/T - 1/T) = exp2(d*K - K)

typedef float  float4v __attribute__((ext_vector_type(4)));
typedef short  short4v __attribute__((ext_vector_type(4)));
typedef short  short8v __attribute__((ext_vector_type(8)));

static __device__ __forceinline__ unsigned short f2bf(float x) {
    // round-to-nearest-even f32 -> bf16 (inputs are finite)
    unsigned u = __builtin_bit_cast(unsigned, x);
    u += 0x7fffu + ((u >> 16) & 1u);
    return (unsigned short)(u >> 16);
}

static __device__ __forceinline__ float fexp2(float x) {
#if __has_builtin(__builtin_amdgcn_exp2f)
    return __builtin_amdgcn_exp2f(x);   // v_exp_f32 directly
#else
    return exp2f(x);                    // lowers to v_exp_f32 via ocml
#endif
}

static __device__ __forceinline__ void gload_lds16(const void* g, void* l) {
    __builtin_amdgcn_global_load_lds(
        (const __attribute__((address_space(1))) unsigned int*)g,
        (__attribute__((address_space(3))) unsigned int*)l, 16, 0, 0);
}

// ---------------- prep kernel (r12, kept): vectorized normalize + bits -------
__global__ void prep_kernel(const float* __restrict__ feat, const float* __restrict__ labels,
                            unsigned short* __restrict__ fnb, unsigned* __restrict__ bits,
                            float* __restrict__ zacc) {
    const int blk = blockIdx.x, t = threadIdx.x;
    if (blk < 512) {
        const int lane = t & 63;
        const int wave = t >> 6;
#pragma unroll
        for (int it = 0; it < 2; ++it) {
            const int b  = blk * 8 + it * 4 + wave;   // row 0..4095
            const int bb = b & (BS - 1);
            const int v  = b >> 11;
            float4v x = *(const float4v*)(feat + (size_t)bb * (2 * EDIM)
                                               + (size_t)v * EDIM + lane * 4);
            float ss = x[0]*x[0] + x[1]*x[1] + x[2]*x[2] + x[3]*x[3];
            ss += __shfl_xor(ss, 1, 64);
            ss += __shfl_xor(ss, 2, 64);
            ss += __shfl_xor(ss, 4, 64);
            ss += __shfl_xor(ss, 8, 64);
            const float inv = 1.0f / fmaxf(sqrtf(ss), 1e-12f);
            short4v o;
            o[0] = (short)f2bf(x[0] * inv);
            o[1] = (short)f2bf(x[1] * inv);
            o[2] = (short)f2bf(x[2] * inv);
            o[3] = (short)f2bf(x[3] * inv);
            *(short4v*)(fnb + (size_t)b * EDIM + lane * 4) = o;
        }
    } else {
        int g = (blk - 512) * 256 + t;   // 0..2047
        unsigned bb = 0;
#pragma unroll
        for (int d = 0; d < 10; ++d)
            bb |= (labels[g * 10 + d] != 0.0f ? 1u : 0u) << d;
        bits[g] = bb;
        // zero S (N*4), Num (N), Cnt (N*4), red[2], done[1] = N*9+3 words
        for (int k = g; k < NROW * 9 + 3; k += 2048) zacc[k] = 0.0f;
    }
}

// ---------------- main kernel: r13 pipeline + 20% leaner epilogue -----------
// Structure IDENTICAL to r13 (16 subtiles, 3 buffers, counted vmcnt(2),
// 2-deep prefetch, (256,4), 4 blocks/CU, zero tail).  r13 proved the stall
// is not barrier-drain; VALUBusy 34% x 52us = 17.7us VALU issue is the
// largest busy share, so this round cuts per-cell VALU with zero structural
// change:
//  (1) exp2 fold: exp((d-1)/T) = exp2(d*K - K), K = INVT*log2e -> saves the
//      internal x*log2e mul of __expf (4 VALU/cell).
//  (2) off-predication removed (v_cmp + 4 cndmask/cell): Sp accumulates the
//      diagonal cell too; the ONE diagonal subtile per wave (st == stDiag,
//      wave-uniform scalar branch) captures dacc into dacD, and a single
//      post-loop undo recomputes e/bd/bh from dacD -- identical f32 inputs
//      through identical instruction sequences -> bit-identical values ->
//      exact cancellation (argmax tie behavior included).  np-side diag
//      condition is ibr[r]&ibr[r] = ibr[r]!=0.
// cpk fields transiently <=17 < 255: safe.  VGPR +16 (dacD); spill tripwire:
// FETCH > 11MB.  Null read pre-committed: main 51-52 unchanged => VALU issue
// not critical-path => declare practical ceiling next round.
// C/D layout (m89/m91): col = lane&15, row = (lane>>4)*4 + reg.
__global__ __launch_bounds__(256, 4) void main_kernel(
    const unsigned short* __restrict__ fnb, const unsigned* __restrict__ bits,
    float* __restrict__ S, float* __restrict__ Num, float* __restrict__ Cnt) {

    __shared__ unsigned short shB[3][16 * 256];   // 3 x 8 KiB, swizzled granules

    const int tid  = threadIdx.x;
    const int lane = tid & 63;
    const int wave = tid >> 6;
    const int quad = lane >> 4;
    const int ml   = lane & 15;
    const int xr   = ml & 7;                   // swizzle XOR for this lane's rows
    const int i0   = blockIdx.x * 64 + wave * 16;
    const int jc0  = blockIdx.y * 256;
    // diagonal subtile for this wave (or -1): block covers the diagonal iff
    // bx>>2 == by; then wave w's 16 i-rows meet j==i in subtile 4*(bx&3)+w.
    const int stDiag = ((blockIdx.x >> 2) == blockIdx.y)
                     ? ((blockIdx.x & 3) * 4 + wave) : -1;

    // A fragments: af[h][kk], 8 x short8 = 32 VGPRs (rows i0..i0+15)
    short8v af[4][2];
    {
        const unsigned short* ap = fnb + (size_t)(i0 + ml) * EDIM + quad * 8;
#pragma unroll
        for (int h = 0; h < 4; ++h)
#pragma unroll
            for (int kk = 0; kk < 2; ++kk)
                af[h][kk] = *(const short8v*)(ap + h * 64 + kk * 32);
    }

    unsigned ibr[4];
#pragma unroll
    for (int r = 0; r < 4; ++r)
        ibr[r] = bits[(i0 + quad * 4 + r) & (BS - 1)];

    // all 16 subtile label-masks hoisted (keeps the loop's vmcnt count exact)
    unsigned jbr[16];
#pragma unroll
    for (int st = 0; st < 16; ++st)
        jbr[st] = bits[(jc0 + st * 16 + ml) & (BS - 1)];

    float    Sp[4][4] = {};
    float    np[4] = {};
    unsigned cpk[4] = {};   // per row: 4 x 8-bit argmax-head counts (<=17/lane)
    float4v  dacD[4];       // diagonal subtile's dacc (captured once)
#pragma unroll
    for (int h = 0; h < 4; ++h) dacD[h] = (float4v){0.f, 0.f, 0.f, 0.f};

    // stage 16 j-rows (8 KiB) of subtile st into shB[buf]; 2 loads/thread
    auto STAGE = [&](int st, int buf) {
#pragma unroll
        for (int q = 0; q < 2; ++q) {
            const int G   = tid + 256 * q;          // LDS 16B-granule index 0..511
            const int row = G >> 5;                 // 0..15
            const int gg  = (G & 31) ^ (row & 7);   // global granule (pre-swizzled src)
            gload_lds16(fnb + (size_t)(jc0 + st * 16 + row) * EDIM + gg * 8,
                        &shB[buf][G * 8]);
        }
    };

    STAGE(0, 0);
    STAGE(1, 1);

#pragma unroll
    for (int st = 0; st < 16; ++st) {
        // counted wait: everything except the newest 2 VMEM ops (= STAGE(st+1))
        // must be complete -> STAGE(st) landed; STAGE(st+1) rides across the
        // barrier (T4).  Last iter: drain.
        if (st < 15) asm volatile("s_waitcnt vmcnt(2)" ::: "memory");
        else         asm volatile("s_waitcnt vmcnt(0)" ::: "memory");
        __builtin_amdgcn_s_barrier();
        __builtin_amdgcn_sched_barrier(0);      // rule #18: no hoist above wait

        const int cur = st % 3;                 // static after full unroll
        const unsigned jb = jbr[st];

        float4v dacc[4];   // [h] -- live range = this subtile only (16 regs)
#pragma unroll
        for (int h = 0; h < 4; ++h) dacc[h] = (float4v){0.f, 0.f, 0.f, 0.f};
#pragma unroll
        for (int h = 0; h < 4; ++h)
#pragma unroll
            for (int kk = 0; kk < 2; ++kk) {
                const int gsw = ((h * 8 + kk * 4 + quad) ^ xr) * 8;  // elem offset
                short8v bf = *(const short8v*)(&shB[cur][ml * 256 + gsw]);
                dacc[h] = __builtin_amdgcn_mfma_f32_16x16x32_bf16(af[h][kk], bf, dacc[h], 0, 0, 0);
            }

        if (st == stDiag) {                     // wave-uniform, once per wave
#pragma unroll
            for (int h = 0; h < 4; ++h) dacD[h] = dacc[h];
        }

#pragma unroll
        for (int r = 0; r < 4; ++r) {
            const float d0 = dacc[0][r];
            const float d1 = dacc[1][r];
            const float d2 = dacc[2][r];
            const float d3 = dacc[3][r];
            // argmax, first index wins ties
            float bd = d0; int bh = 0;
            if (d1 > bd) { bd = d1; bh = 1; }
            if (d2 > bd) { bd = d2; bh = 2; }
            if (d3 > bd) { bd = d3; bh = 3; }
            const float e0 = fexp2(fmaf(d0, KEXP, -KEXP));
            const float e1 = fexp2(fmaf(d1, KEXP, -KEXP));
            const float e2 = fexp2(fmaf(d2, KEXP, -KEXP));
            const float e3 = fexp2(fmaf(d3, KEXP, -KEXP));
            Sp[r][0] += e0; Sp[r][1] += e1; Sp[r][2] += e2; Sp[r][3] += e3;
            if (ibr[r] & jb) {
                np[r] += bd;              // raw dot; * INVT at flush
                cpk[r] += 1u << (bh * 8);
            }
        }

        if (st + 2 < 16) STAGE(st + 2, (st + 2) % 3);
    }

    // undo the diagonal cell (exact: recompute from the captured dacc values
    // through the identical instruction sequence -> bit-identical e/bd/bh)
    if (stDiag >= 0) {
#pragma unroll
        for (int r = 0; r < 4; ++r) {
            const float d0 = dacD[0][r];
            const float d1 = dacD[1][r];
            const float d2 = dacD[2][r];
            const float d3 = dacD[3][r];
            float bd = d0; int bh = 0;
            if (d1 > bd) { bd = d1; bh = 1; }
            if (d2 > bd) { bd = d2; bh = 2; }
            if (d3 > bd) { bd = d3; bh = 3; }
            const float e0 = fexp2(fmaf(d0, KEXP, -KEXP));
            const float e1 = fexp2(fmaf(d1, KEXP, -KEXP));
            const float e2 = fexp2(fmaf(d2, KEXP, -KEXP));
            const float e3 = fexp2(fmaf(d3, KEXP, -KEXP));
            const bool mine = (ml == quad * 4 + r);   // lane holding j == i
            if (mine) {
                Sp[r][0] -= e0; Sp[r][1] -= e1; Sp[r][2] -= e2; Sp[r][3] -= e3;
                if (ibr[r]) {                 // diag mask = ibr & ibr
                    np[r] -= bd;
                    cpk[r] -= 1u << (bh * 8);
                }
            }
        }
    }

    // reduce the 16 lanes sharing each row, then one global atomic per value
#pragma unroll
    for (int r = 0; r < 4; ++r) {
        const int i = i0 + quad * 4 + r;
        float v[9];
        v[0] = np[r];
#pragma unroll
        for (int h = 0; h < 4; ++h) v[1 + h] = Sp[r][h];
#pragma unroll
        for (int h = 0; h < 4; ++h) v[5 + h] = (float)((cpk[r] >> (8 * h)) & 255u);
#pragma unroll
        for (int k = 0; k < 9; ++k) {
            float x = v[k];
            x += __shfl_xor(x, 1, 64);
            x += __shfl_xor(x, 2, 64);
            x += __shfl_xor(x, 4, 64);
            x += __shfl_xor(x, 8, 64);
            v[k] = x;
        }
        if (ml == 0) {
            atomicAdd(&Num[i], v[0] * INVT);
#pragma unroll
            for (int h = 0; h < 4; ++h) atomicAdd(&S[i * 4 + h], v[1 + h]);
#pragma unroll
            for (int h = 0; h < 4; ++h) atomicAdd(&Cnt[i * 4 + h], v[5 + h]);
        }
    }
}

// ---------------- final reduction: 16 blocks, last block writes out --------
__global__ void final_kernel(const float* __restrict__ S, const float* __restrict__ Num,
                             const float* __restrict__ Cnt, float* __restrict__ red,
                             unsigned* __restrict__ done, float* __restrict__ out) {
    const int tid = threadIdx.x;
    const int i = blockIdx.x * 256 + tid;   // grid 16 x 256 = 4096 rows exactly
    float c = 0.f;
    float numr = Num[i];
#pragma unroll
    for (int h = 0; h < 4; ++h) {
        float sh = S[i * 4 + h];
        float ch = Cnt[i * 4 + h];
        numr -= ch * (INVT + logf(sh));
        c += ch;
    }
    float ls = 0.f, lc = 0.f;
    if (c > 0.f) { ls = -(numr / c); lc = 1.f; }

    __shared__ float rs[256], rc[256];
    rs[tid] = ls; rc[tid] = lc;
    __syncthreads();
    for (int s = 128; s > 0; s >>= 1) {
        if (tid < s) { rs[tid] += rs[tid + s]; rc[tid] += rc[tid + s]; }
        __syncthreads();
    }
    if (tid == 0) {
        atomicAdd(&red[0], rs[0]);
        atomicAdd(&red[1], rc[0]);
        __threadfence();
        if (atomicAdd(done, 1u) == 15u) {
            float s = atomicAdd(&red[0], 0.0f);
            float cc = atomicAdd(&red[1], 0.0f);
            out[0] = s / cc;
        }
    }
}

extern "C" void kernel_launch(void* const* d_in, const int* in_sizes, int n_in,
                              void* d_out, int out_size, void* d_ws, size_t ws_size,
                              hipStream_t stream) {
    const float* feat = (const float*)d_in[0];    // (2048, 2, 256) f32
    const float* labels = (const float*)d_in[1];  // (2048, 10) f32
    float* out = (float*)d_out;

    char* ws = (char*)d_ws;
    unsigned short* fnb = (unsigned short*)ws;                     // N*E bf16 (2 MB)
    float* S = (float*)(ws + (size_t)NROW * EDIM * sizeof(unsigned short));
    float* Num = S + NROW * 4;
    float* Cnt = Num + NROW;
    float* red = Cnt + NROW * 4;              // red[0]=sum, red[1]=count
    unsigned* done = (unsigned*)(red + 2);    // completion counter
    unsigned* bits = done + 1;                // BS label bitmasks

    prep_kernel<<<520, 256, 0, stream>>>(feat, labels, fnb, bits, S);
    main_kernel<<<dim3(64, 16), 256, 0, stream>>>(fnb, bits, S, Num, Cnt);
    final_kernel<<<16, 256, 0, stream>>>(S, Num, Cnt, red, done, out);
}

// Round 15
// 106.464 us; speedup vs baseline: 3.8499x; 3.8499x over previous
//
#include <hip/hip_runtime.h>
#include <math.h>

// Problem constants
#define BS    2048            // batch
#define NROW  4096            // B*V = N
#define EDIM  256
#define INVT  (1.0f/0.07f)
#define KEXP  20.609929155556623f   // INVT * log2(e): exp(d/T - 1/T) = exp2(d*K - K)

typedef float  float4v __attribute__((ext_vector_type(4)));
typedef short  short4v __attribute__((ext_vector_type(4)));
typedef short  short8v __attribute__((ext_vector_type(8)));

static __device__ __forceinline__ unsigned short f2bf(float x) {
    // round-to-nearest-even f32 -> bf16 (inputs are finite)
    unsigned u = __builtin_bit_cast(unsigned, x);
    u += 0x7fffu + ((u >> 16) & 1u);
    return (unsigned short)(u >> 16);
}

static __device__ __forceinline__ float fexp2(float x) {
#if __has_builtin(__builtin_amdgcn_exp2f)
    return __builtin_amdgcn_exp2f(x);   // v_exp_f32 directly
#else
    return exp2f(x);
#endif
}

static __device__ __forceinline__ void gload_lds16(const void* g, void* l) {
    __builtin_amdgcn_global_load_lds(
        (const __attribute__((address_space(1))) unsigned int*)g,
        (__attribute__((address_space(3))) unsigned int*)l, 16, 0, 0);
}

// ---------------- prep kernel (r12, kept): vectorized normalize + bits -------
__global__ void prep_kernel(const float* __restrict__ feat, const float* __restrict__ labels,
                            unsigned short* __restrict__ fnb, unsigned* __restrict__ bits,
                            float* __restrict__ zacc) {
    const int blk = blockIdx.x, t = threadIdx.x;
    if (blk < 512) {
        const int lane = t & 63;
        const int wave = t >> 6;
#pragma unroll
        for (int it = 0; it < 2; ++it) {
            const int b  = blk * 8 + it * 4 + wave;   // row 0..4095
            const int bb = b & (BS - 1);
            const int v  = b >> 11;
            float4v x = *(const float4v*)(feat + (size_t)bb * (2 * EDIM)
                                               + (size_t)v * EDIM + lane * 4);
            float ss = x[0]*x[0] + x[1]*x[1] + x[2]*x[2] + x[3]*x[3];
            ss += __shfl_xor(ss, 1, 64);
            ss += __shfl_xor(ss, 2, 64);
            ss += __shfl_xor(ss, 4, 64);
            ss += __shfl_xor(ss, 8, 64);
            const float inv = 1.0f / fmaxf(sqrtf(ss), 1e-12f);
            short4v o;
            o[0] = (short)f2bf(x[0] * inv);
            o[1] = (short)f2bf(x[1] * inv);
            o[2] = (short)f2bf(x[2] * inv);
            o[3] = (short)f2bf(x[3] * inv);
            *(short4v*)(fnb + (size_t)b * EDIM + lane * 4) = o;
        }
    } else {
        int g = (blk - 512) * 256 + t;   // 0..2047
        unsigned bb = 0;
#pragma unroll
        for (int d = 0; d < 10; ++d)
            bb |= (labels[g * 10 + d] != 0.0f ? 1u : 0u) << d;
        bits[g] = bb;
        // zero S (N*4), Num (N), Cnt (N*4), red[2], done[1] = N*9+3 words
        for (int k = g; k < NROW * 9 + 3; k += 2048) zacc[k] = 0.0f;
    }
}

// ---------------- main kernel: r13 VERBATIM + zero-register exp2 fold --------
// r14 post-mortem: dacD capture + diag-undo spilled (FETCH 308MB, WRITE
// 472MB, 7x slower) -- the (256,4) reg budget is saturated at r13's VGPR 64;
// ANY addition spills.  Off-predication removal is permanently closed at
// this occupancy.  This round: r13 byte-identical EXCEPT __expf -> exp2 fold
// (strictly fewer ops, zero register delta) -- simultaneously the
// revert-to-best and the only clean VALU probe left.
// Pre-committed: null (main 51-52) => VALU off-path, r13-class = practical
// plateau (both pipes <35%, latency-structural, 7 structural alts exhausted).
// Pipeline: 16 subtiles of 16 rows, 3 buffers (24 KiB), 2-deep prefetch,
// counted s_waitcnt vmcnt(2) + raw s_barrier + sched_barrier(0) (rule #18);
// jbr[16] hoisted so the vmcnt count is exact (loop fully unrolled, rule #20).
// C/D layout (m89/m91): col = lane&15, row = (lane>>4)*4 + reg.
__global__ __launch_bounds__(256, 4) void main_kernel(
    const unsigned short* __restrict__ fnb, const unsigned* __restrict__ bits,
    float* __restrict__ S, float* __restrict__ Num, float* __restrict__ Cnt) {

    __shared__ unsigned short shB[3][16 * 256];   // 3 x 8 KiB, swizzled granules

    const int tid  = threadIdx.x;
    const int lane = tid & 63;
    const int wave = tid >> 6;
    const int quad = lane >> 4;
    const int ml   = lane & 15;
    const int xr   = ml & 7;                   // swizzle XOR for this lane's rows
    const int i0   = blockIdx.x * 64 + wave * 16;
    const int jc0  = blockIdx.y * 256;

    // A fragments: af[h][kk], 8 x short8 = 32 VGPRs (rows i0..i0+15)
    short8v af[4][2];
    {
        const unsigned short* ap = fnb + (size_t)(i0 + ml) * EDIM + quad * 8;
#pragma unroll
        for (int h = 0; h < 4; ++h)
#pragma unroll
            for (int kk = 0; kk < 2; ++kk)
                af[h][kk] = *(const short8v*)(ap + h * 64 + kk * 32);
    }

    unsigned ibr[4];
#pragma unroll
    for (int r = 0; r < 4; ++r)
        ibr[r] = bits[(i0 + quad * 4 + r) & (BS - 1)];

    // all 16 subtile label-masks hoisted (keeps the loop's vmcnt count exact)
    unsigned jbr[16];
#pragma unroll
    for (int st = 0; st < 16; ++st)
        jbr[st] = bits[(jc0 + st * 16 + ml) & (BS - 1)];

    float    Sp[4][4] = {};
    float    np[4] = {};
    unsigned cpk[4] = {};   // per row: 4 x 8-bit argmax-head counts (<=16/lane)

    // stage 16 j-rows (8 KiB) of subtile st into shB[buf]; 2 loads/thread
    auto STAGE = [&](int st, int buf) {
#pragma unroll
        for (int q = 0; q < 2; ++q) {
            const int G   = tid + 256 * q;          // LDS 16B-granule index 0..511
            const int row = G >> 5;                 // 0..15
            const int gg  = (G & 31) ^ (row & 7);   // global granule (pre-swizzled src)
            gload_lds16(fnb + (size_t)(jc0 + st * 16 + row) * EDIM + gg * 8,
                        &shB[buf][G * 8]);
        }
    };

    STAGE(0, 0);
    STAGE(1, 1);

#pragma unroll
    for (int st = 0; st < 16; ++st) {
        // counted wait: everything except the newest 2 VMEM ops (= STAGE(st+1))
        // must be complete -> STAGE(st) landed; STAGE(st+1) rides across the
        // barrier (T4).  Last iter: drain.
        if (st < 15) asm volatile("s_waitcnt vmcnt(2)" ::: "memory");
        else         asm volatile("s_waitcnt vmcnt(0)" ::: "memory");
        __builtin_amdgcn_s_barrier();
        __builtin_amdgcn_sched_barrier(0);      // rule #18: no hoist above wait

        const int cur = st % 3;                 // static after full unroll
        const int j0  = jc0 + st * 16;
        const unsigned jb = jbr[st];

        float4v dacc[4];   // [h] -- live range = this subtile only (16 regs)
#pragma unroll
        for (int h = 0; h < 4; ++h) dacc[h] = (float4v){0.f, 0.f, 0.f, 0.f};
#pragma unroll
        for (int h = 0; h < 4; ++h)
#pragma unroll
            for (int kk = 0; kk < 2; ++kk) {
                const int gsw = ((h * 8 + kk * 4 + quad) ^ xr) * 8;  // elem offset
                short8v bf = *(const short8v*)(&shB[cur][ml * 256 + gsw]);
                dacc[h] = __builtin_amdgcn_mfma_f32_16x16x32_bf16(af[h][kk], bf, dacc[h], 0, 0, 0);
            }

        const int j = j0 + ml;
#pragma unroll
        for (int r = 0; r < 4; ++r) {
            const int i = i0 + quad * 4 + r;
            const float d0 = dacc[0][r];
            const float d1 = dacc[1][r];
            const float d2 = dacc[2][r];
            const float d3 = dacc[3][r];
            // argmax, first index wins ties
            float bd = d0; int bh = 0;
            if (d1 > bd) { bd = d1; bh = 1; }
            if (d2 > bd) { bd = d2; bh = 2; }
            if (d3 > bd) { bd = d3; bh = 3; }
            const bool off = (i != j);
            const float e0 = fexp2(fmaf(d0, KEXP, -KEXP));
            const float e1 = fexp2(fmaf(d1, KEXP, -KEXP));
            const float e2 = fexp2(fmaf(d2, KEXP, -KEXP));
            const float e3 = fexp2(fmaf(d3, KEXP, -KEXP));
            if (off) {
                Sp[r][0] += e0; Sp[r][1] += e1; Sp[r][2] += e2; Sp[r][3] += e3;
            }
            if (off && (ibr[r] & jb)) {
                np[r] += bd;              // raw dot; * INVT at flush
                cpk[r] += 1u << (bh * 8);
            }
        }

        if (st + 2 < 16) STAGE(st + 2, (st + 2) % 3);
    }

    // reduce the 16 lanes sharing each row, then one global atomic per value
#pragma unroll
    for (int r = 0; r < 4; ++r) {
        const int i = i0 + quad * 4 + r;
        float v[9];
        v[0] = np[r];
#pragma unroll
        for (int h = 0; h < 4; ++h) v[1 + h] = Sp[r][h];
#pragma unroll
        for (int h = 0; h < 4; ++h) v[5 + h] = (float)((cpk[r] >> (8 * h)) & 255u);
#pragma unroll
        for (int k = 0; k < 9; ++k) {
            float x = v[k];
            x += __shfl_xor(x, 1, 64);
            x += __shfl_xor(x, 2, 64);
            x += __shfl_xor(x, 4, 64);
            x += __shfl_xor(x, 8, 64);
            v[k] = x;
        }
        if (ml == 0) {
            atomicAdd(&Num[i], v[0] * INVT);
#pragma unroll
            for (int h = 0; h < 4; ++h) atomicAdd(&S[i * 4 + h], v[1 + h]);
#pragma unroll
            for (int h = 0; h < 4; ++h) atomicAdd(&Cnt[i * 4 + h], v[5 + h]);
        }
    }
}

// ---------------- final reduction: 16 blocks, last block writes out --------
__global__ void final_kernel(const float* __restrict__ S, const float* __restrict__ Num,
                             const float* __restrict__ Cnt, float* __restrict__ red,
                             unsigned* __restrict__ done, float* __restrict__ out) {
    const int tid = threadIdx.x;
    const int i = blockIdx.x * 256 + tid;   // grid 16 x 256 = 4096 rows exactly
    float c = 0.f;
    float numr = Num[i];
#pragma unroll
    for (int h = 0; h < 4; ++h) {
        float sh = S[i * 4 + h];
        float ch = Cnt[i * 4 + h];
        numr -= ch * (INVT + logf(sh));
        c += ch;
    }
    float ls = 0.f, lc = 0.f;
    if (c > 0.f) { ls = -(numr / c); lc = 1.f; }

    __shared__ float rs[256], rc[256];
    rs[tid] = ls; rc[tid] = lc;
    __syncthreads();
    for (int s = 128; s > 0; s >>= 1) {
        if (tid < s) { rs[tid] += rs[tid + s]; rc[tid] += rc[tid + s]; }
        __syncthreads();
    }
    if (tid == 0) {
        atomicAdd(&red[0], rs[0]);
        atomicAdd(&red[1], rc[0]);
        __threadfence();
        if (atomicAdd(done, 1u) == 15u) {
            float s = atomicAdd(&red[0], 0.0f);
            float cc = atomicAdd(&red[1], 0.0f);
            out[0] = s / cc;
        }
    }
}

extern "C" void kernel_launch(void* const* d_in, const int* in_sizes, int n_in,
                              void* d_out, int out_size, void* d_ws, size_t ws_size,
                              hipStream_t stream) {
    const float* feat = (const float*)d_in[0];    // (2048, 2, 256) f32
    const float* labels = (const float*)d_in[1];  // (2048, 10) f32
    float* out = (float*)d_out;

    char* ws = (char*)d_ws;
    unsigned short* fnb = (unsigned short*)ws;                     // N*E bf16 (2 MB)
    float* S = (float*)(ws + (size_t)NROW * EDIM * sizeof(unsigned short));
    float* Num = S + NROW * 4;
    float* Cnt = Num + NROW;
    float* red = Cnt + NROW * 4;              // red[0]=sum, red[1]=count
    unsigned* done = (unsigned*)(red + 2);    // completion counter
    unsigned* bits = done + 1;                // BS label bitmasks

    prep_kernel<<<520, 256, 0, stream>>>(feat, labels, fnb, bits, S);
    main_kernel<<<dim3(64, 16), 256, 0, stream>>>(fnb, bits, S, Num, Cnt);
    final_kernel<<<16, 256, 0, stream>>>(S, Num, Cnt, red, done, out);
}